// Round 4
// baseline (23015.866 us; speedup 1.0000x reference)
//
#include <hip/hip_runtime.h>

// NewGRU: B=64, T=2048, D=256, U=256
// R3 = instrumentation round.
//   proj_kernel + scan_t<0>: VERBATIM round-1 pair (known-correct, absmax 0.0078)
//   -> d_out.  Then four probe dispatches (results -> d_ws only), each a
//   one-variable delta vs scan_t<0>, to partition the ~7300-cycle step:
//     clk_probe  : 2.1M dependent FMAs (known cycles) -> effective clock
//     scan_t<1>  : no s_barrier (waitcnts kept)       -> barrier sync cost
//     scan_t<2>  : no MFMA (ds_reads kept live)       -> MFMA + reg-move cost
//     scan_t<4>  : no transcendentals (clamped lin)   -> trans-pipe cost

#define TT 2048
#define DD 256

typedef __attribute__((ext_vector_type(8))) short short8;          // 8 x bf16 bits
typedef __attribute__((ext_vector_type(4))) unsigned short us4;    // 4 x bf16 bits
typedef __attribute__((ext_vector_type(2))) unsigned int uint2v;   // 8B store
typedef __attribute__((ext_vector_type(4))) float f32x4;

__device__ __forceinline__ unsigned short f2bf(float f) {          // RTN f32->bf16
  unsigned u = __float_as_uint(f);
  return (unsigned short)((u + 0x7FFFu + ((u >> 16) & 1u)) >> 16);
}
__device__ __forceinline__ float bf2f(unsigned short s) {
  return __uint_as_float(((unsigned)s) << 16);
}
__device__ __forceinline__ unsigned pk2(float lo, float hi) {      // 2xbf16 pack
  unsigned a = __float_as_uint(lo) + 0x8000u;
  unsigned b = __float_as_uint(hi) + 0x8000u;
  return (b & 0xFFFF0000u) | (a >> 16);
}
__device__ __forceinline__ float sigmoid_f(float x) {
  return __builtin_amdgcn_rcpf(1.f + __builtin_amdgcn_exp2f(x * -1.44269504f));
}
__device__ __forceinline__ float tanh_f(float x) {
  return 1.f - 2.f * __builtin_amdgcn_rcpf(1.f + __builtin_amdgcn_exp2f(x * 2.88539008f));
}
__device__ __forceinline__ f32x4 mfma16(short8 a, short8 b, f32x4 c) {
  return __builtin_amdgcn_mfma_f32_16x16x32_bf16(a, b, c, 0, 0, 0);
}
// XOR-swizzle for 16-row x 256-col bf16 tiles (512B rows).
__device__ __forceinline__ unsigned swz(unsigned row, unsigned byteInRow) {
  return row * 512u + (byteInRow ^ ((row & 7u) << 4));
}

// ---------------------------------------------------------------------------
// proj_kernel: verbatim round-1 (passed).
// ---------------------------------------------------------------------------
__global__ __launch_bounds__(512) void proj_kernel(
    const float* __restrict__ x,
    const float* __restrict__ Wxu, const float* __restrict__ Wxr,
    const float* __restrict__ Wxo,
    const float* __restrict__ bu, const float* __restrict__ br,
    const float* __restrict__ bo,
    unsigned short* __restrict__ Ap)
{
  __shared__ alignas(16) unsigned short x_lds[16 * 256];

  const int tid = threadIdx.x;
  const int w = tid >> 6, l = tid & 63;
  const int q = l >> 4, b16 = l & 15;
  const int bblk = blockIdx.x & 3;
  const int tc = blockIdx.x >> 2;
  const int b0 = bblk * 16;

  short8 wx[6][8];
  f32x4 bbv[6];
#pragma unroll
  for (int n = 0; n < 6; ++n) {
    int ntg = w * 6 + n;
    const float* Wg = (ntg < 16) ? Wxu : (ntg < 32) ? Wxr : Wxo;
    const float* bg = (ntg < 16) ? bu : (ntg < 32) ? br : bo;
    int ct = ntg & 15;
    int col = ct * 16 + b16;
    int c0 = ct * 16 + q * 4;
    bbv[n] = (f32x4){bg[c0], bg[c0 + 1], bg[c0 + 2], bg[c0 + 3]};
#pragma unroll
    for (int kt = 0; kt < 8; ++kt) {
      int k0 = kt * 32 + q * 8;
      short8 f;
#pragma unroll
      for (int j = 0; j < 8; ++j) f[j] = (short)f2bf(Wg[(k0 + j) * 256 + col]);
      wx[n][kt] = f;
    }
  }

  for (int it = 0; it < 8; ++it) {
    const int t = tc * 8 + it;
    {
      int row = tid >> 5;
      int part = tid & 31;
      const float* src = x + (((size_t)(b0 + row) * TT + t) * DD) + part * 8;
      float4 f0 = *(const float4*)(src);
      float4 f1 = *(const float4*)(src + 4);
      us4 s0 = { f2bf(f0.x), f2bf(f0.y), f2bf(f0.z), f2bf(f0.w) };
      us4 s1 = { f2bf(f1.x), f2bf(f1.y), f2bf(f1.z), f2bf(f1.w) };
      unsigned base = swz((unsigned)row, (unsigned)(part * 16));
      *(us4*)((char*)x_lds + base) = s0;
      *(us4*)((char*)x_lds + base + 8) = s1;
    }
    __syncthreads();

    f32x4 acc[6];
#pragma unroll
    for (int n = 0; n < 6; ++n) acc[n] = bbv[n];
#pragma unroll
    for (int kt = 0; kt < 8; ++kt) {
      short8 xa = *(const short8*)((const char*)x_lds + swz(b16, kt * 64 + q * 16));
#pragma unroll
      for (int n = 0; n < 6; ++n) acc[n] = mfma16(wx[n][kt], xa, acc[n]);
    }
    __syncthreads();

#pragma unroll
    for (int n = 0; n < 6; ++n) {
      int ntg = w * 6 + n;
      int g = ntg >> 4, ct = ntg & 15;
      us4 st = { f2bf(acc[n][0]), f2bf(acc[n][1]), f2bf(acc[n][2]), f2bf(acc[n][3]) };
      size_t base = (((size_t)t * 3 + g) * 4 + bblk) * 4096
                    + ct * 256 + q * 64 + b16 * 4;
      *(us4*)(Ap + base) = st;
    }
  }
}

// ---------------------------------------------------------------------------
// scan_t<MODE>: round-1 scan, parameterized.
//   MODE&1 : remove both s_barrier (keep waitcnts)        [probe only]
//   MODE&2 : replace MFMAs with cheap adds (reads live)   [probe only]
//   MODE&4 : replace sigmoid/tanh with clamped linear     [probe only]
//   MODE=0 : exact round-1 behavior -> real output.
// ---------------------------------------------------------------------------
template<int MODE>
__global__ __launch_bounds__(512, 2) void scan_t(
    const float* __restrict__ Whu, const float* __restrict__ Whr,
    const float* __restrict__ Wro,
    const unsigned short* __restrict__ Ap,
    float* __restrict__ outp)
{
  __shared__ alignas(16) unsigned short h_lds[16 * 256];
  __shared__ alignas(16) unsigned short r_lds[16 * 256];

  const int tid = threadIdx.x;
  const int w = tid >> 6, l = tid & 63;
  const int q = l >> 4, b16 = l & 15;
  const int bblk = blockIdx.x;
  const int cw = w * 32;

  auto SIG = [&](float v) -> float {
    if constexpr (MODE & 4) return fminf(fmaxf(__builtin_fmaf(v, 0.25f, 0.5f), 0.f), 1.f);
    else return sigmoid_f(v);
  };
  auto THF = [&](float v) -> float {
    if constexpr (MODE & 4) return fminf(fmaxf(v * 0.5f, -1.f), 1.f);
    else return tanh_f(v);
  };

  short8 wbu[2][8], wbr[2][8], wbo[2][8];
#pragma unroll
  for (int n = 0; n < 2; ++n) {
    const int col = cw + n * 16 + b16;
#pragma unroll
    for (int kt = 0; kt < 8; ++kt) {
      const int k0 = kt * 32 + q * 8;
      short8 fu, fr, fo;
#pragma unroll
      for (int j = 0; j < 8; ++j) {
        fu[j] = (short)f2bf(Whu[(k0 + j) * 256 + col]);
        fr[j] = (short)f2bf(Whr[(k0 + j) * 256 + col]);
        fo[j] = (short)f2bf(Wro[(k0 + j) * 256 + col]);
      }
      wbu[n][kt] = fu; wbr[n][kt] = fr; wbo[n][kt] = fo;
    }
  }

  const unsigned rdbase = (unsigned)(b16 * 512 + ((q * 16) ^ ((b16 & 7) << 4)));
  const unsigned wrb0 = (unsigned)(b16 * 512 + ((unsigned)((cw + q * 4) * 2) ^ ((b16 & 7) << 4)));
  const unsigned wrb1 = (unsigned)(b16 * 512 + ((unsigned)((cw + 16 + q * 4) * 2) ^ ((b16 & 7) << 4)));

  const unsigned lane_off = (unsigned)(w * 512 + q * 64 + b16 * 4);
  const unsigned aoff_u = (unsigned)((0 * 4 + bblk) * 4096) + lane_off;
  const unsigned aoff_r = (unsigned)((1 * 4 + bblk) * 4096) + lane_off;
  const unsigned aoff_o = (unsigned)((2 * 4 + bblk) * 4096) + lane_off;

  *(short8*)(&h_lds[tid * 8]) = (short8){0, 0, 0, 0, 0, 0, 0, 0};

  float hm0 = 0, hm1 = 0, hm2 = 0, hm3 = 0, hm4 = 0, hm5 = 0, hm6 = 0, hm7 = 0;

  us4 Pu0 = *(const us4*)(Ap + aoff_u);
  us4 Pu1 = *(const us4*)(Ap + aoff_u + 256);
  us4 Pr0 = *(const us4*)(Ap + aoff_r);
  us4 Pr1 = *(const us4*)(Ap + aoff_r + 256);
  us4 Nu0 = Pu0, Nu1 = Pu1, Nr0 = Pr0, Nr1 = Pr1;

  __syncthreads();

#define STEP_BODY(T, PU0, PU1, PR0, PR1, NU0, NU1, NR0, NR1)                     \
  {                                                                              \
    const unsigned short* cb = Ap + (size_t)(T) * 49152u;                        \
    us4 aO0 = *(const us4*)(cb + aoff_o);                                        \
    us4 aO1 = *(const us4*)(cb + aoff_o + 256);                                  \
    if ((T) + 1 < TT) {                                                          \
      const unsigned short* nb = cb + 49152u;                                    \
      NU0 = *(const us4*)(nb + aoff_u);                                          \
      NU1 = *(const us4*)(nb + aoff_u + 256);                                    \
      NR0 = *(const us4*)(nb + aoff_r);                                          \
      NR1 = *(const us4*)(nb + aoff_r + 256);                                    \
    }                                                                            \
    f32x4 accu0 = (f32x4){bf2f(PU0[0]), bf2f(PU0[1]), bf2f(PU0[2]), bf2f(PU0[3])}; \
    f32x4 accu1 = (f32x4){bf2f(PU1[0]), bf2f(PU1[1]), bf2f(PU1[2]), bf2f(PU1[3])}; \
    f32x4 accr0 = (f32x4){bf2f(PR0[0]), bf2f(PR0[1]), bf2f(PR0[2]), bf2f(PR0[3])}; \
    f32x4 accr1 = (f32x4){bf2f(PR1[0]), bf2f(PR1[1]), bf2f(PR1[2]), bf2f(PR1[3])}; \
    _Pragma("unroll")                                                            \
    for (int kt = 0; kt < 8; ++kt) {                                             \
      short8 ha = *(const short8*)((const char*)h_lds + (rdbase ^ (unsigned)(kt << 6))); \
      if constexpr (!(MODE & 2)) {                                               \
        accu0 = mfma16(wbu[0][kt], ha, accu0);                                   \
        accu1 = mfma16(wbu[1][kt], ha, accu1);                                   \
        accr0 = mfma16(wbr[0][kt], ha, accr0);                                   \
        accr1 = mfma16(wbr[1][kt], ha, accr1);                                   \
      } else {                                                                   \
        float tv = bf2f((unsigned short)ha[0]);                                  \
        accu0[0] += tv; accu1[0] += tv; accr0[0] += tv; accr1[0] += tv;          \
      }                                                                          \
    }                                                                            \
    accu0[0] = SIG(accu0[0]); accu0[1] = SIG(accu0[1]);                          \
    accu0[2] = SIG(accu0[2]); accu0[3] = SIG(accu0[3]);                          \
    accu1[0] = SIG(accu1[0]); accu1[1] = SIG(accu1[1]);                          \
    accu1[2] = SIG(accu1[2]); accu1[3] = SIG(accu1[3]);                          \
    {                                                                            \
      float ra0 = SIG(accr0[0]), ra1 = SIG(accr0[1]);                            \
      float ra2 = SIG(accr0[2]), ra3 = SIG(accr0[3]);                            \
      float rb0 = SIG(accr1[0]), rb1 = SIG(accr1[1]);                            \
      float rb2 = SIG(accr1[2]), rb3 = SIG(accr1[3]);                            \
      *(uint2v*)((char*)r_lds + wrb0) = (uint2v){pk2(ra0, ra1), pk2(ra2, ra3)};  \
      *(uint2v*)((char*)r_lds + wrb1) = (uint2v){pk2(rb0, rb1), pk2(rb2, rb3)};  \
    }                                                                            \
    asm volatile("s_waitcnt lgkmcnt(0)" ::: "memory");                           \
    if constexpr (!(MODE & 1)) {                                                 \
      __builtin_amdgcn_s_barrier();                                              \
      asm volatile("" ::: "memory");                                             \
    }                                                                            \
    f32x4 acco0 = (f32x4){bf2f(aO0[0]), bf2f(aO0[1]), bf2f(aO0[2]), bf2f(aO0[3])}; \
    f32x4 acco1 = (f32x4){bf2f(aO1[0]), bf2f(aO1[1]), bf2f(aO1[2]), bf2f(aO1[3])}; \
    _Pragma("unroll")                                                            \
    for (int kt = 0; kt < 8; ++kt) {                                             \
      short8 ra = *(const short8*)((const char*)r_lds + (rdbase ^ (unsigned)(kt << 6))); \
      if constexpr (!(MODE & 2)) {                                               \
        acco0 = mfma16(wbo[0][kt], ra, acco0);                                   \
        acco1 = mfma16(wbo[1][kt], ra, acco1);                                   \
      } else {                                                                   \
        float tv = bf2f((unsigned short)ra[0]);                                  \
        acco0[0] += tv; acco1[0] += tv;                                          \
      }                                                                          \
    }                                                                            \
    hm0 += accu0[0] * (THF(acco0[0]) - hm0);                                     \
    hm1 += accu0[1] * (THF(acco0[1]) - hm1);                                     \
    hm2 += accu0[2] * (THF(acco0[2]) - hm2);                                     \
    hm3 += accu0[3] * (THF(acco0[3]) - hm3);                                     \
    hm4 += accu1[0] * (THF(acco1[0]) - hm4);                                     \
    hm5 += accu1[1] * (THF(acco1[1]) - hm5);                                     \
    hm6 += accu1[2] * (THF(acco1[2]) - hm6);                                     \
    hm7 += accu1[3] * (THF(acco1[3]) - hm7);                                     \
    *(uint2v*)((char*)h_lds + wrb0) = (uint2v){pk2(hm0, hm1), pk2(hm2, hm3)};    \
    *(uint2v*)((char*)h_lds + wrb1) = (uint2v){pk2(hm4, hm5), pk2(hm6, hm7)};    \
    asm volatile("s_waitcnt lgkmcnt(0)" ::: "memory");                           \
    if constexpr (!(MODE & 1)) {                                                 \
      __builtin_amdgcn_s_barrier();                                              \
      asm volatile("" ::: "memory");                                             \
    }                                                                            \
  }

  for (int t = 0; t < TT; t += 2) {
    STEP_BODY(t,     Pu0, Pu1, Pr0, Pr1, Nu0, Nu1, Nr0, Nr1)
    STEP_BODY(t + 1, Nu0, Nu1, Nr0, Nr1, Pu0, Pu1, Pr0, Pr1)
  }
#undef STEP_BODY

  const int orow = bblk * 16 + b16;
  *(f32x4*)(&outp[orow * 256 + cw + q * 4])      = (f32x4){hm0, hm1, hm2, hm3};
  *(f32x4*)(&outp[orow * 256 + cw + 16 + q * 4]) = (f32x4){hm4, hm5, hm6, hm7};
}

// ---------------------------------------------------------------------------
// clk_probe: 8192 x 256 = 2.097M dependent FMAs per thread.
// Expected ~8.4M cycles: ~3.5 ms @ 2.4 GHz. If >= ~6 ms, the near-idle chip
// is clock-throttled and ALL scan numbers rescale.
// ---------------------------------------------------------------------------
__global__ void clk_probe(const float* __restrict__ cin, float* __restrict__ outp) {
  float a = cin[threadIdx.x & 63];
  float c = cin[64 + (threadIdx.x & 63)] * 0.001f;
  for (int i = 0; i < 8192; ++i) {
#pragma unroll
    for (int j = 0; j < 256; ++j) a = __builtin_fmaf(a, 0.5f, c);
  }
  outp[blockIdx.x * 512 + threadIdx.x] = a;
}

__global__ void ws_signal_kernel(float* out, float v) {
  out[blockIdx.x * 256 + threadIdx.x] = v;
}

extern "C" void kernel_launch(void* const* d_in, const int* in_sizes, int n_in,
                              void* d_out, int out_size, void* d_ws, size_t ws_size,
                              hipStream_t stream) {
  const float* x   = (const float*)d_in[0];
  const float* Wxu = (const float*)d_in[1];
  const float* Whu = (const float*)d_in[2];
  const float* bu  = (const float*)d_in[3];
  const float* Wxr = (const float*)d_in[4];
  const float* Whr = (const float*)d_in[5];
  const float* br  = (const float*)d_in[6];
  const float* Wxo = (const float*)d_in[7];
  const float* Wro = (const float*)d_in[8];
  const float* bo  = (const float*)d_in[9];
  float* out = (float*)d_out;

  const size_t needed = (size_t)TT * 3 * 4 * 4096 * 2;  // 192 MiB bf16 A'
  if (ws_size < needed) {
    ws_signal_kernel<<<64, 256, 0, stream>>>(out, (float)(ws_size >> 20));
    return;
  }
  unsigned short* Ap = (unsigned short*)d_ws;
  float* vout = (float*)d_ws;   // probe outputs overwrite A' AFTER the real scan

  proj_kernel<<<1024, 512, 0, stream>>>(x, Wxu, Wxr, Wxo, bu, br, bo, Ap);
  scan_t<0><<<4, 512, 0, stream>>>(Whu, Whr, Wro, Ap, out);        // REAL output

  // --- probes (d_ws only; A' is re-written by proj on every call) ---
  clk_probe<<<4, 512, 0, stream>>>(x, vout);
  scan_t<1><<<4, 512, 0, stream>>>(Whu, Whr, Wro, Ap, vout + 16384);  // no barrier
  scan_t<2><<<4, 512, 0, stream>>>(Whu, Whr, Wro, Ap, vout + 32768);  // no MFMA
  scan_t<4><<<4, 512, 0, stream>>>(Whu, Whr, Wro, Ap, vout + 49152);  // no trans
}

// Round 5
// 3924.227 us; speedup vs baseline: 5.8651x; 5.8651x over previous
//
#include <hip/hip_runtime.h>

// NewGRU: B=64, T=2048, D=256, U=256
// R4: scan with (a) 544B-stride h/r LDS tiles (verified conflict-free for both
// b128 B-frag reads and b64 C-frag writes, pure-add kt addressing), (b) A' in a
// 4-step LDS ring via global_load_lds with counted vmcnt(6) (never drained) and
// clamped-prefetch for a uniform loop, (c) no per-step global loads/addressing.

#define TT 2048
#define DD 256

typedef __attribute__((ext_vector_type(8))) short short8;          // 8 x bf16 bits
typedef __attribute__((ext_vector_type(4))) unsigned short us4;    // 4 x bf16 bits
typedef __attribute__((ext_vector_type(2))) unsigned int uint2v;   // 8B store
typedef __attribute__((ext_vector_type(4))) float f32x4;

__device__ __forceinline__ unsigned short f2bf(float f) {          // RTN f32->bf16
  unsigned u = __float_as_uint(f);
  return (unsigned short)((u + 0x7FFFu + ((u >> 16) & 1u)) >> 16);
}
__device__ __forceinline__ float bf2f(unsigned short s) {
  return __uint_as_float(((unsigned)s) << 16);
}
__device__ __forceinline__ unsigned pk2(float lo, float hi) {      // 2xbf16 pack
  unsigned a = __float_as_uint(lo) + 0x8000u;
  unsigned b = __float_as_uint(hi) + 0x8000u;
  return (b & 0xFFFF0000u) | (a >> 16);
}
__device__ __forceinline__ float sigmoid_f(float x) {
  return __builtin_amdgcn_rcpf(1.f + __builtin_amdgcn_exp2f(x * -1.44269504f));
}
__device__ __forceinline__ float tanh_f(float x) {
  return 1.f - 2.f * __builtin_amdgcn_rcpf(1.f + __builtin_amdgcn_exp2f(x * 2.88539008f));
}
__device__ __forceinline__ f32x4 mfma16(short8 a, short8 b, f32x4 c) {
  return __builtin_amdgcn_mfma_f32_16x16x32_bf16(a, b, c, 0, 0, 0);
}
__device__ __forceinline__ void load_lds16(const void* gp, void* lp) {
  __builtin_amdgcn_global_load_lds((__attribute__((address_space(1))) void*)(gp),
                                   (__attribute__((address_space(3))) void*)(lp),
                                   16, 0, 0);
}
// XOR swizzle used only by proj_kernel's x tile (verified R1).
__device__ __forceinline__ unsigned swz(unsigned row, unsigned byteInRow) {
  return row * 512u + (byteInRow ^ ((row & 7u) << 4));
}

// ---------------------------------------------------------------------------
// proj_kernel: R1 math (verified); store layout makes each scan-lane's TWO
// C-init fragments one contiguous 16B slot:
//   offset(shorts) = (ct>>1)*512 + lane*8 + (ct&1)*4  within (t,g,bblk) region.
// Scan lane l (q=l>>4,b=l&15) of wave w then reads 16B at w*512 + l*8:
//   [us4 cols 32w+q*4+j | us4 cols 32w+16+q*4+j] for batch b.
// ---------------------------------------------------------------------------
__global__ __launch_bounds__(512) void proj_kernel(
    const float* __restrict__ x,
    const float* __restrict__ Wxu, const float* __restrict__ Wxr,
    const float* __restrict__ Wxo,
    const float* __restrict__ bu, const float* __restrict__ br,
    const float* __restrict__ bo,
    unsigned short* __restrict__ Ap)
{
  __shared__ alignas(16) unsigned short x_lds[16 * 256];

  const int tid = threadIdx.x;
  const int w = tid >> 6, l = tid & 63;
  const int q = l >> 4, b16 = l & 15;
  const int bblk = blockIdx.x & 3;
  const int tc = blockIdx.x >> 2;
  const int b0 = bblk * 16;

  short8 wx[6][8];
  f32x4 bbv[6];
#pragma unroll
  for (int n = 0; n < 6; ++n) {
    int ntg = w * 6 + n;
    const float* Wg = (ntg < 16) ? Wxu : (ntg < 32) ? Wxr : Wxo;
    const float* bg = (ntg < 16) ? bu : (ntg < 32) ? br : bo;
    int ct = ntg & 15;
    int col = ct * 16 + b16;
    int c0 = ct * 16 + q * 4;
    bbv[n] = (f32x4){bg[c0], bg[c0 + 1], bg[c0 + 2], bg[c0 + 3]};
#pragma unroll
    for (int kt = 0; kt < 8; ++kt) {
      int k0 = kt * 32 + q * 8;
      short8 f;
#pragma unroll
      for (int j = 0; j < 8; ++j) f[j] = (short)f2bf(Wg[(k0 + j) * 256 + col]);
      wx[n][kt] = f;
    }
  }

  for (int it = 0; it < 8; ++it) {
    const int t = tc * 8 + it;
    {
      int row = tid >> 5;
      int part = tid & 31;
      const float* src = x + (((size_t)(b0 + row) * TT + t) * DD) + part * 8;
      float4 f0 = *(const float4*)(src);
      float4 f1 = *(const float4*)(src + 4);
      us4 s0 = { f2bf(f0.x), f2bf(f0.y), f2bf(f0.z), f2bf(f0.w) };
      us4 s1 = { f2bf(f1.x), f2bf(f1.y), f2bf(f1.z), f2bf(f1.w) };
      unsigned base = swz((unsigned)row, (unsigned)(part * 16));
      *(us4*)((char*)x_lds + base) = s0;
      *(us4*)((char*)x_lds + base + 8) = s1;
    }
    __syncthreads();

    f32x4 acc[6];
#pragma unroll
    for (int n = 0; n < 6; ++n) acc[n] = bbv[n];
#pragma unroll
    for (int kt = 0; kt < 8; ++kt) {
      short8 xa = *(const short8*)((const char*)x_lds + swz(b16, kt * 64 + q * 16));
#pragma unroll
      for (int n = 0; n < 6; ++n) acc[n] = mfma16(wx[n][kt], xa, acc[n]);  // transposed
    }
    __syncthreads();

#pragma unroll
    for (int n = 0; n < 6; ++n) {
      int ntg = w * 6 + n;
      int g = ntg >> 4, ct = ntg & 15;
      us4 st = { f2bf(acc[n][0]), f2bf(acc[n][1]), f2bf(acc[n][2]), f2bf(acc[n][3]) };
      size_t base = (((size_t)t * 3 + g) * 4 + bblk) * 4096
                    + (ct >> 1) * 512 + l * 8 + (ct & 1) * 4;
      *(us4*)(Ap + base) = st;
    }
  }
}

// ---------------------------------------------------------------------------
// scan_kernel: 4 blocks x 512 threads (8 waves).
// LDS map (bytes):
//   ring  [0, 98304)      : 4 slots x 3 gates x 8KB (A' C-init fragments)
//   h     [98304, 107008) : 16 rows x 544B (conflict-free padded stride)
//   r     [107008, 115712)
// Per step: vmcnt(6) (counted, never drained) -> issue prefetch t+3 (clamped)
// -> phase1 (ring u/r/o reads + h@W MFMA + r write) -> barrier ->
// phase2 (r@Wro MFMA + u/tanh/h update + h write) -> barrier.
// ---------------------------------------------------------------------------
#define RING_SLOT 24576
#define HOFF 98304
#define ROFF 107008

__global__ __launch_bounds__(512, 2) void scan_kernel(
    const float* __restrict__ Whu, const float* __restrict__ Whr,
    const float* __restrict__ Wro,
    const unsigned short* __restrict__ Ap,
    float* __restrict__ out)
{
  __shared__ alignas(16) char lds8[115712];

  const int tid = threadIdx.x;
  const int w = tid >> 6, l = tid & 63;
  const int q = l >> 4, b16 = l & 15;
  const int bblk = blockIdx.x;
  const int cw = w * 32;

  // --- register/AGPR-resident recurrent weights (identical bytes to R1)
  short8 wbu[2][8], wbr[2][8], wbo[2][8];
#pragma unroll
  for (int n = 0; n < 2; ++n) {
    const int col = cw + n * 16 + b16;
#pragma unroll
    for (int kt = 0; kt < 8; ++kt) {
      const int k0 = kt * 32 + q * 8;
      short8 fu, fr, fo;
#pragma unroll
      for (int j = 0; j < 8; ++j) {
        fu[j] = (short)f2bf(Whu[(k0 + j) * 256 + col]);
        fr[j] = (short)f2bf(Whr[(k0 + j) * 256 + col]);
        fo[j] = (short)f2bf(Wro[(k0 + j) * 256 + col]);
      }
      wbu[n][kt] = fu; wbr[n][kt] = fr; wbo[n][kt] = fo;
    }
  }

  // --- addresses (544B row stride; conflict-free, pure-add in kt)
  const unsigned rowb = (unsigned)(b16 * 544);
  const char* hrd = lds8 + HOFF + rowb + q * 16;           // + kt*64 (imm)
  const char* rrd = lds8 + ROFF + rowb + q * 16;
  char* hwr0 = lds8 + HOFF + rowb + (cw + q * 4) * 2;      // 8B; second at +32
  char* rwr0 = lds8 + ROFF + rowb + (cw + q * 4) * 2;
  const char* ringr = lds8 + w * 1024 + l * 16;            // + slot*24576 + g*8192

  // per-lane A' global source (shorts): + t*49152 + g*16384
  const unsigned short* apl = Ap + (size_t)bblk * 4096 + w * 512 + l * 8;

  // zero h(-1) tile (whole 8704B region)
  for (int i = tid; i < 8704 / 4; i += 512) *(int*)(lds8 + HOFF + i * 4) = 0;

  float hm0 = 0, hm1 = 0, hm2 = 0, hm3 = 0, hm4 = 0, hm5 = 0, hm6 = 0, hm7 = 0;

  // prologue: preload slots 0,1,2
#pragma unroll
  for (int t0 = 0; t0 < 3; ++t0) {
    const unsigned short* s = apl + (size_t)t0 * 49152u;
    char* d = lds8 + (t0 & 3) * RING_SLOT + w * 1024;
    load_lds16(s,         d);
    load_lds16(s + 16384, d + 8192);
    load_lds16(s + 32768, d + 16384);
  }
  __syncthreads();   // h zeros visible (one-time)

#define STEP_BODY(T)                                                             \
  {                                                                              \
    /* counted wait: drain only this step's 3 oldest ring loads */               \
    asm volatile("s_waitcnt vmcnt(6)" ::: "memory");                             \
    { /* prefetch step T+3 (clamped; duplicate loads write identical bytes) */   \
      int tp = (T) + 3; if (tp > TT - 1) tp = TT - 1;                            \
      const unsigned short* s = apl + (size_t)tp * 49152u;                       \
      char* d = lds8 + (tp & 3) * RING_SLOT + w * 1024;                          \
      load_lds16(s,         d);                                                  \
      load_lds16(s + 16384, d + 8192);                                           \
      load_lds16(s + 32768, d + 16384);                                          \
    }                                                                            \
    const char* rp = ringr + ((T) & 3) * RING_SLOT;                              \
    short8 aU = *(const short8*)(rp);                                            \
    short8 aR = *(const short8*)(rp + 8192);                                     \
    short8 aO = *(const short8*)(rp + 16384);   /* o read early (own slice) */   \
    f32x4 accu0 = (f32x4){bf2f((unsigned short)aU[0]), bf2f((unsigned short)aU[1]), \
                          bf2f((unsigned short)aU[2]), bf2f((unsigned short)aU[3])}; \
    f32x4 accu1 = (f32x4){bf2f((unsigned short)aU[4]), bf2f((unsigned short)aU[5]), \
                          bf2f((unsigned short)aU[6]), bf2f((unsigned short)aU[7])}; \
    f32x4 accr0 = (f32x4){bf2f((unsigned short)aR[0]), bf2f((unsigned short)aR[1]), \
                          bf2f((unsigned short)aR[2]), bf2f((unsigned short)aR[3])}; \
    f32x4 accr1 = (f32x4){bf2f((unsigned short)aR[4]), bf2f((unsigned short)aR[5]), \
                          bf2f((unsigned short)aR[6]), bf2f((unsigned short)aR[7])}; \
    _Pragma("unroll")                                                            \
    for (int kt = 0; kt < 8; ++kt) {                                             \
      short8 ha = *(const short8*)(hrd + kt * 64);                               \
      accr0 = mfma16(wbr[0][kt], ha, accr0);                                     \
      accr1 = mfma16(wbr[1][kt], ha, accr1);                                     \
      accu0 = mfma16(wbu[0][kt], ha, accu0);                                     \
      accu1 = mfma16(wbu[1][kt], ha, accu1);                                     \
    }                                                                            \
    { /* r = sigmoid, pack, write */                                             \
      float ra0 = sigmoid_f(accr0[0]), ra1 = sigmoid_f(accr0[1]);                \
      float ra2 = sigmoid_f(accr0[2]), ra3 = sigmoid_f(accr0[3]);                \
      float rb0 = sigmoid_f(accr1[0]), rb1 = sigmoid_f(accr1[1]);                \
      float rb2 = sigmoid_f(accr1[2]), rb3 = sigmoid_f(accr1[3]);                \
      *(uint2v*)(rwr0)      = (uint2v){pk2(ra0, ra1), pk2(ra2, ra3)};            \
      *(uint2v*)(rwr0 + 32) = (uint2v){pk2(rb0, rb1), pk2(rb2, rb3)};            \
    }                                                                            \
    asm volatile("s_waitcnt lgkmcnt(0)" ::: "memory");                           \
    __builtin_amdgcn_s_barrier();                                                \
    asm volatile("" ::: "memory");                                               \
    /* ---- phase 2 ---- */                                                      \
    f32x4 acco0 = (f32x4){bf2f((unsigned short)aO[0]), bf2f((unsigned short)aO[1]), \
                          bf2f((unsigned short)aO[2]), bf2f((unsigned short)aO[3])}; \
    f32x4 acco1 = (f32x4){bf2f((unsigned short)aO[4]), bf2f((unsigned short)aO[5]), \
                          bf2f((unsigned short)aO[6]), bf2f((unsigned short)aO[7])}; \
    _Pragma("unroll")                                                            \
    for (int kt = 0; kt < 8; ++kt) {                                             \
      short8 ra = *(const short8*)(rrd + kt * 64);                               \
      acco0 = mfma16(wbo[0][kt], ra, acco0);                                     \
      acco1 = mfma16(wbo[1][kt], ra, acco1);                                     \
    }                                                                            \
    {                                                                            \
      float u0 = sigmoid_f(accu0[0]), u1 = sigmoid_f(accu0[1]);                  \
      float u2 = sigmoid_f(accu0[2]), u3 = sigmoid_f(accu0[3]);                  \
      float u4 = sigmoid_f(accu1[0]), u5 = sigmoid_f(accu1[1]);                  \
      float u6 = sigmoid_f(accu1[2]), u7 = sigmoid_f(accu1[3]);                  \
      hm0 += u0 * (tanh_f(acco0[0]) - hm0);                                      \
      hm1 += u1 * (tanh_f(acco0[1]) - hm1);                                      \
      hm2 += u2 * (tanh_f(acco0[2]) - hm2);                                      \
      hm3 += u3 * (tanh_f(acco0[3]) - hm3);                                      \
      hm4 += u4 * (tanh_f(acco1[0]) - hm4);                                      \
      hm5 += u5 * (tanh_f(acco1[1]) - hm5);                                      \
      hm6 += u6 * (tanh_f(acco1[2]) - hm6);                                      \
      hm7 += u7 * (tanh_f(acco1[3]) - hm7);                                      \
      *(uint2v*)(hwr0)      = (uint2v){pk2(hm0, hm1), pk2(hm2, hm3)};            \
      *(uint2v*)(hwr0 + 32) = (uint2v){pk2(hm4, hm5), pk2(hm6, hm7)};            \
    }                                                                            \
    asm volatile("s_waitcnt lgkmcnt(0)" ::: "memory");                           \
    __builtin_amdgcn_s_barrier();                                                \
    asm volatile("" ::: "memory");                                               \
  }

  for (int t = 0; t < TT; t += 2) {
    STEP_BODY(t)
    STEP_BODY(t + 1)
  }
#undef STEP_BODY

  const int orow = bblk * 16 + b16;
  const int c0 = cw + q * 4;
  *(f32x4*)(&out[orow * 256 + c0])      = (f32x4){hm0, hm1, hm2, hm3};
  *(f32x4*)(&out[orow * 256 + c0 + 16]) = (f32x4){hm4, hm5, hm6, hm7};
}

__global__ void ws_signal_kernel(float* out, float v) {
  out[blockIdx.x * 256 + threadIdx.x] = v;
}

extern "C" void kernel_launch(void* const* d_in, const int* in_sizes, int n_in,
                              void* d_out, int out_size, void* d_ws, size_t ws_size,
                              hipStream_t stream) {
  const float* x   = (const float*)d_in[0];
  const float* Wxu = (const float*)d_in[1];
  const float* Whu = (const float*)d_in[2];
  const float* bu  = (const float*)d_in[3];
  const float* Wxr = (const float*)d_in[4];
  const float* Whr = (const float*)d_in[5];
  const float* br  = (const float*)d_in[6];
  const float* Wxo = (const float*)d_in[7];
  const float* Wro = (const float*)d_in[8];
  const float* bo  = (const float*)d_in[9];
  float* out = (float*)d_out;

  const size_t needed = (size_t)TT * 3 * 4 * 4096 * 2;  // 192 MiB bf16 A'
  if (ws_size < needed) {
    ws_signal_kernel<<<64, 256, 0, stream>>>(out, (float)(ws_size >> 20));
    return;
  }
  unsigned short* Ap = (unsigned short*)d_ws;
  proj_kernel<<<1024, 512, 0, stream>>>(x, Wxu, Wxr, Wxo, bu, br, bo, Ap);
  scan_kernel<<<4, 512, 0, stream>>>(Whu, Whr, Wro, Ap, out);
}